// Round 1
// baseline (163.728 us; speedup 1.0000x reference)
//
#include <hip/hip_runtime.h>
#include <stdint.h>

typedef __attribute__((ext_vector_type(8))) short s16x8;
typedef __attribute__((ext_vector_type(4))) float f32x4;

__device__ __forceinline__ short f2bf(float f){
  union { float f; uint32_t u; } v; v.f = f;
  uint32_t u = v.u;
  u += 0x7fffu + ((u >> 16) & 1u);
  return (short)(u >> 16);
}
__device__ __forceinline__ float bf2f(short s){
  union { uint32_t u; float f; } v; v.u = ((uint32_t)(uint16_t)s) << 16;
  return v.f;
}
__device__ __forceinline__ float sigm(float x){
  return __fdividef(1.f, 1.f + __expf(-x));
}
__device__ __forceinline__ float tanh_fast(float x){
  return 1.f - __fdividef(2.f, __expf(2.f * x) + 1.f);
}

#define MFMA16(a, b, c) __builtin_amdgcn_mfma_f32_16x16x32_bf16((a), (b), (c), 0, 0, 0)

// Fused TemporalEncoder: conv1(1->16,k3,causal)+ReLU -> conv2(16->32,k3,causal)+ReLU
// -> GRU(32->64) over T=100, emit final hidden state.
// Block = 256 threads (4 waves) owns 16 sequences end-to-end.
// Wave w owns hidden dims [16w,16w+16) and gate tiles {w, w+4, w+8} (r,z,n cols match).
__global__ __launch_bounds__(256, 2) void te_fused(
    const float* __restrict__ x,
    const float* __restrict__ w1, const float* __restrict__ b1,
    const float* __restrict__ w2, const float* __restrict__ b2,
    const float* __restrict__ Wih, const float* __restrict__ Whh,
    const float* __restrict__ bih, const float* __restrict__ bhh,
    float* __restrict__ out)
{
  constexpr int T = 100;
  __shared__ float x_s[16 * T];          // staged input rows
  __shared__ short hA[2][2][16 * 72];    // [buf][hi/lo][seq][72-padded k] bf16 h for A-frags
  __shared__ short ring[4][16 * 24];     // c1 ring: [slot=t%4][seq][24-padded ch(16)] bf16
  __shared__ short s_s[2][16 * 40];      // conv2 output s_t: [buf][seq][40-padded ch(32)] bf16

  const int tid  = threadIdx.x;
  const int lane = tid & 63;
  const int wv   = tid >> 6;    // wave 0..3
  const int l15  = lane & 15;
  const int lg   = lane >> 4;   // 0..3
  const int seq0 = blockIdx.x * 16;
  const int sl   = tid >> 4;    // conv1: seq 0..15
  const int chc  = tid & 15;    // conv1: channel 0..15

  // ---- stage x (contiguous 16*100 floats per block, 16B aligned) ----
  {
    const float4* gx = reinterpret_cast<const float4*>(x + (size_t)seq0 * T);
    float4* sx = reinterpret_cast<float4*>(x_s);
    for (int i = tid; i < (16 * T) / 4; i += 256) sx[i] = gx[i];
  }
  // zero h buffer 0 (hi+lo) and the whole c1 ring (stale slots must be finite)
  {
    int* p = reinterpret_cast<int*>(&hA[0][0][0]);
    for (int i = tid; i < (2 * 16 * 72) / 2; i += 256) p[i] = 0;
    int* q = reinterpret_cast<int*>(&ring[0][0]);
    for (int i = tid; i < (4 * 16 * 24) / 2; i += 256) q[i] = 0;
  }

  // ---- build weight B-fragments in registers ----
  // B[k][n] layout: lane holds n = l&15 (+tile base), k = (l>>4)*8 + j
  s16x8 WhhHi[3][2], WhhLo[3][2], WihHi[3], WihLo[3];
  float bihv[3], bhhv[3];
#pragma unroll
  for (int g = 0; g < 3; ++g) {
    const int n = 64 * g + 16 * wv + l15;      // global gate row
    bihv[g] = bih[n];
    bhhv[g] = bhh[n];
#pragma unroll
    for (int ks = 0; ks < 2; ++ks) {
      const float* p = Whh + n * 64 + ks * 32 + lg * 8;
#pragma unroll
      for (int j = 0; j < 8; ++j) {
        float f = p[j];
        short hi = f2bf(f);
        WhhHi[g][ks][j] = hi;
        WhhLo[g][ks][j] = f2bf(f - bf2f(hi));
      }
    }
    const float* q = Wih + n * 32 + lg * 8;
#pragma unroll
    for (int j = 0; j < 8; ++j) {
      float f = q[j];
      short hi = f2bf(f);
      WihHi[g][j] = hi;
      WihLo[g][j] = f2bf(f - bf2f(hi));
    }
  }

  // conv2 B-fragments per ring phase (used by waves 0,1; ntile = wv&1)
  // flat k = slot*16 + i ; slot holding tau==slot (mod 4); phase ph = u%4 (u = conv2 output time)
  // d = (slot-ph)&3 : d==0 -> tap 2, d==3 -> tap 1, d==2 -> tap 0, d==1 -> outside window (B=0)
  s16x8 cW[4][2];
  float b2v;
  {
    const int nt = wv & 1;
    const int ch = 16 * nt + l15;
    b2v = b2[ch];
#pragma unroll
    for (int ph = 0; ph < 4; ++ph)
#pragma unroll
      for (int ks = 0; ks < 2; ++ks) {
        s16x8 h8;
#pragma unroll
        for (int j = 0; j < 8; ++j) {
          const int k = ks * 32 + lg * 8 + j;
          const int st = k >> 4, ii = k & 15;
          const int d = (st - ph) & 3;
          float f = 0.f;
          if (d != 1) {
            const int a = (d == 0) ? 2 : ((d == 3) ? 1 : 0);
            f = w2[ch * 48 + ii * 3 + a];
          }
          h8[j] = f2bf(f);
        }
        cW[ph][ks] = h8;
      }
  }

  // conv1 per-thread weights
  const float w1v0 = w1[chc * 3 + 0], w1v1 = w1[chc * 3 + 1], w1v2 = w1[chc * 3 + 2];
  const float b1v = b1[chc];

  __syncthreads();

  float xa_r = x_s[sl * T + 0];
  float xb_r = x_s[sl * T + 1];

  // conv2 A-frag addressing: k-group k0 = ks*32 + lg*8 -> slot k0>>4, offset (k0&15)
  const int i0a = (lg & 1) * 8;
  const int sA0 = lg >> 1;
  const int sA1 = 2 + (lg >> 1);

  auto conv2_step = [&](int ph, int buf) {
    s16x8 a0 = *reinterpret_cast<const s16x8*>(&ring[sA0][l15 * 24 + i0a]);
    s16x8 a1 = *reinterpret_cast<const s16x8*>(&ring[sA1][l15 * 24 + i0a]);
    s16x8 cb0, cb1;
    switch (ph) {   // static frag indices (avoid scratch spill from runtime indexing)
      case 0: cb0 = cW[0][0]; cb1 = cW[0][1]; break;
      case 1: cb0 = cW[1][0]; cb1 = cW[1][1]; break;
      case 2: cb0 = cW[2][0]; cb1 = cW[2][1]; break;
      default: cb0 = cW[3][0]; cb1 = cW[3][1]; break;
    }
    f32x4 sa = { b2v, b2v, b2v, b2v };
    sa = MFMA16(a0, cb0, sa);
    sa = MFMA16(a1, cb1, sa);
    short* sw = &s_s[buf][0];
#pragma unroll
    for (int i2 = 0; i2 < 4; ++i2) {
      float v = sa[i2];
      v = v > 0.f ? v : 0.f;
      sw[(lg * 4 + i2) * 40 + (wv & 1) * 16 + l15] = f2bf(v);
    }
  };

  // ---- prologue: c1(0) -> s(0) -> c1(1) ----
  {
    float c = b1v + w1v2 * xa_r;              // c1(0): taps x(-2)=x(-1)=0
    c = c > 0.f ? c : 0.f;
    ring[0][sl * 24 + chc] = f2bf(c);
  }
  __syncthreads();
  if (wv < 2) conv2_step(0, 0);               // s(0); slots 1..3 are zero
  {
    float c = b1v + w1v1 * xa_r + w1v2 * xb_r; // c1(1)
    c = c > 0.f ? c : 0.f;
    ring[1][sl * 24 + chc] = f2bf(c);
  }
  __syncthreads();

  float hreg[4] = {0.f, 0.f, 0.f, 0.f};

  for (int t = 0; t < T; ++t) {
    // A-fragments: s(t) and h(t-1) hi/lo
    s16x8 as_ = *reinterpret_cast<const s16x8*>(&s_s[t & 1][l15 * 40 + lg * 8]);
    const short* hb = &hA[t & 1][0][0];
    const short* lb = &hA[t & 1][1][0];
    const int ho = l15 * 72 + lg * 8;
    s16x8 ah0 = *reinterpret_cast<const s16x8*>(hb + ho);
    s16x8 ah1 = *reinterpret_cast<const s16x8*>(hb + ho + 32);
    s16x8 al0 = *reinterpret_cast<const s16x8*>(lb + ho);
    s16x8 al1 = *reinterpret_cast<const s16x8*>(lb + ho + 32);

    f32x4 xpa[3], gha[3];
#pragma unroll
    for (int g = 0; g < 3; ++g) {
      f32x4 xa4 = { bihv[g], bihv[g], bihv[g], bihv[g] };
      xa4 = MFMA16(as_, WihHi[g], xa4);        // xp = s @ Wih^T (split-2 on W)
      xa4 = MFMA16(as_, WihLo[g], xa4);
      xpa[g] = xa4;
      f32x4 ga = { bhhv[g], bhhv[g], bhhv[g], bhhv[g] };
      ga = MFMA16(ah0, WhhHi[g][0], ga);       // gh = h @ Whh^T, 3-term split product
      ga = MFMA16(ah1, WhhHi[g][1], ga);
      ga = MFMA16(al0, WhhHi[g][0], ga);
      ga = MFMA16(al1, WhhHi[g][1], ga);
      ga = MFMA16(ah0, WhhLo[g][0], ga);
      ga = MFMA16(ah1, WhhLo[g][1], ga);
      gha[g] = ga;
    }

    // pipeline: produce s(t+1) and c1(t+2) for later steps
    if (t < T - 1 && wv < 2) conv2_step((t + 1) & 3, (t + 1) & 1);

    if (t < T - 2) {
      float xc = x_s[sl * T + t + 2];
      float c = b1v + w1v0 * xa_r + w1v1 * xb_r + w1v2 * xc;  // c1(t+2)
      c = c > 0.f ? c : 0.f;
      ring[(t + 2) & 3][sl * 24 + chc] = f2bf(c);
      xa_r = xb_r; xb_r = xc;
    }

    // GRU elementwise; D layout: seq = lg*4+i2, hidden dim j = 16*wv + l15
    short* hwh = &hA[(t + 1) & 1][0][0];
    short* hwl = &hA[(t + 1) & 1][1][0];
#pragma unroll
    for (int i2 = 0; i2 < 4; ++i2) {
      float r = sigm(xpa[0][i2] + gha[0][i2]);
      float z = sigm(xpa[1][i2] + gha[1][i2]);
      float nn = tanh_fast(xpa[2][i2] + r * gha[2][i2]);
      float h = (1.f - z) * nn + z * hreg[i2];
      hreg[i2] = h;
      short hi = f2bf(h);
      short lo = f2bf(h - bf2f(hi));
      const int idx = (lg * 4 + i2) * 72 + 16 * wv + l15;
      hwh[idx] = hi;
      hwl[idx] = lo;
    }
    __syncthreads();
  }

#pragma unroll
  for (int i2 = 0; i2 < 4; ++i2) {
    out[(size_t)(seq0 + lg * 4 + i2) * 64 + 16 * wv + l15] = hreg[i2];
  }
}

extern "C" void kernel_launch(void* const* d_in, const int* in_sizes, int n_in,
                              void* d_out, int out_size, void* d_ws, size_t ws_size,
                              hipStream_t stream)
{
  (void)in_sizes; (void)n_in; (void)d_ws; (void)ws_size; (void)out_size;
  const float* x   = (const float*)d_in[0];
  const float* w1  = (const float*)d_in[1];
  const float* b1  = (const float*)d_in[2];
  const float* w2  = (const float*)d_in[3];
  const float* b2  = (const float*)d_in[4];
  const float* Wih = (const float*)d_in[5];
  const float* Whh = (const float*)d_in[6];
  const float* bih = (const float*)d_in[7];
  const float* bhh = (const float*)d_in[8];
  float* out = (float*)d_out;
  te_fused<<<512, 256, 0, stream>>>(x, w1, b1, w2, b2, Wih, Whh, bih, bhh, out);
}